// Round 3
// baseline (13132.303 us; speedup 1.0000x reference)
//
#include <hip/hip_runtime.h>
#include <math.h>

// RNNLayer: out[t] = tanh(x[t] @ Wx + b + h_{t-1} @ Wh), h_{-1} = h0
// S=128, B=128, D=1024, fp32.
//
// Phase 1: gemm_xp writes xp = x@Wx + b into d_out (same layout as output).
// Phase 2: ONE persistent kernel (256 WGs) runs all 128 timesteps, separated
//          by a manual epoch grid barrier in d_ws (monotone counter).
//          Co-residency: 64 KB LDS -> >=2 blocks/CU capacity on 256 CUs for
//          256 blocks; blocks never retire before the end, so spin is safe.

#define DIM 1024
#define BATCH 128
#define SEQ 128
#define BD (BATCH * DIM)
#define NBLK 256

// ---------------------------------------------------------------------------
// Phase 1: C[M,1024] = A[M,1024] @ W[1024,1024] + bias, M = S*B = 16384
// (unchanged: ~471 us, 72 TF)
// ---------------------------------------------------------------------------
__global__ __launch_bounds__(256) void gemm_xp(
    const float* __restrict__ A, const float* __restrict__ W,
    const float* __restrict__ bias, float* __restrict__ C)
{
    __shared__ float As[32][68];   // [k][m]
    __shared__ float Ws[32][68];   // [k][n]

    const int tid  = threadIdx.x;
    const int trow = tid / 16;
    const int tcol = tid % 16;
    const int rowBase = blockIdx.y * 64;
    const int colBase = blockIdx.x * 64;

    const int lam = tid / 8;
    const int laf = tid % 8;
    const int lwk = tid / 16;
    const int lwf = tid % 16;

    float acc[4][4];
    #pragma unroll
    for (int i = 0; i < 4; ++i)
        #pragma unroll
        for (int j = 0; j < 4; ++j) acc[i][j] = 0.f;

    for (int k0 = 0; k0 < DIM; k0 += 32) {
        #pragma unroll
        for (int rr = 0; rr < 2; ++rr) {
            const int m = lam + rr * 32;
            const float4 v = *(const float4*)&A[(size_t)(rowBase + m) * DIM + k0 + laf * 4];
            As[laf * 4 + 0][m] = v.x;
            As[laf * 4 + 1][m] = v.y;
            As[laf * 4 + 2][m] = v.z;
            As[laf * 4 + 3][m] = v.w;
        }
        #pragma unroll
        for (int rr = 0; rr < 2; ++rr) {
            const int k = lwk + rr * 16;
            *(float4*)&Ws[k][lwf * 4] =
                *(const float4*)&W[(size_t)(k0 + k) * DIM + colBase + lwf * 4];
        }
        __syncthreads();

        #pragma unroll
        for (int kk = 0; kk < 32; ++kk) {
            const float4 a4 = *(const float4*)&As[kk][trow * 4];
            const float4 w4 = *(const float4*)&Ws[kk][tcol * 4];
            const float av[4] = {a4.x, a4.y, a4.z, a4.w};
            const float wv[4] = {w4.x, w4.y, w4.z, w4.w};
            #pragma unroll
            for (int i = 0; i < 4; ++i)
                #pragma unroll
                for (int j = 0; j < 4; ++j)
                    acc[i][j] += av[i] * wv[j];
        }
        __syncthreads();
    }

    #pragma unroll
    for (int i = 0; i < 4; ++i) {
        const int row = rowBase + trow * 4 + i;
        const int col = colBase + tcol * 4;
        const float4 bv = *(const float4*)&bias[col];
        float4 o;
        o.x = acc[i][0] + bv.x;
        o.y = acc[i][1] + bv.y;
        o.z = acc[i][2] + bv.z;
        o.w = acc[i][3] + bv.w;
        *(float4*)&C[(size_t)row * DIM + col] = o;
    }
}

// ---------------------------------------------------------------------------
// Manual grid barrier: monotone epoch counter in global memory.
// Release: per-thread __threadfence() before arrive; acquire: __threadfence()
// after spin (invalidates L1 / remote-L2 lines per agent-scope semantics).
// ---------------------------------------------------------------------------
__device__ __forceinline__ void grid_barrier(unsigned* bar, unsigned target) {
    __threadfence();                 // release my writes device-wide
    __syncthreads();
    if (threadIdx.x == 0) {
        __hip_atomic_fetch_add(bar, 1u, __ATOMIC_RELEASE, __HIP_MEMORY_SCOPE_AGENT);
        while (__hip_atomic_load(bar, __ATOMIC_RELAXED, __HIP_MEMORY_SCOPE_AGENT) < target)
            __builtin_amdgcn_s_sleep(1);
    }
    __syncthreads();
    __threadfence();                 // acquire before reading others' writes
}

// ---------------------------------------------------------------------------
// Phase 2: persistent scan.
// Grid: 256 WGs x 256 threads. WG = 8 cols (Wh slice in LDS) x 64 batches.
// Lane l of wave w: c = l&7 (col in slice), p = l>>3; batches bL = w*8+p,
// bH = bL+32 -> 2 outputs/lane, 512 outputs/WG.
// Per step: 8 k-chunks of 128; h chunk staged to LDS (XOR-swizzled float4
// layout, conflict-free) with register-prefetch pipeline.
// LDS: WhS 32 KB + hS4 32 KB = 64 KB.
// ---------------------------------------------------------------------------
__global__ __launch_bounds__(256) void rnn_scan(
    const float* __restrict__ h0,
    const float* __restrict__ Wh,
    float* out,
    unsigned* bar)
{
    __shared__ float  WhS[256][8][4];   // [j][c][i] = Wh[4j+i][C0+c]
    __shared__ float4 hS4[64][32];      // cell (b,jj) stored at [b][jj ^ (b&7)]

    const int tid  = threadIdx.x;
    const int cgid = blockIdx.x >> 1;       // 0..127 column group
    const int bg   = blockIdx.x & 1;        // 0..1 batch half
    const int C0 = cgid * 8;
    const int B0 = bg * 64;

    // ---- stage Wh column slice into LDS (once) ----
    for (int idx = tid; idx < 8192; idx += 256) {
        const int c = idx & 7;
        const int k = idx >> 3;
        WhS[k >> 2][c][k & 3] = Wh[(size_t)k * DIM + C0 + c];
    }

    // compute-lane mapping
    const int w  = tid >> 6;
    const int ll = tid & 63;
    const int c  = ll & 7;
    const int p  = ll >> 3;
    const int bL = w * 8 + p;     // 0..31 local batch
    const int bH = bL + 32;

    // staging mapping: thread loads 8 float4 of row sb, float4-idx sj0..sj0+7
    const int sb   = tid >> 2;          // 0..63
    const int sj0  = (tid & 3) * 8;
    const int sswz = sb & 7;

    __syncthreads();

    for (int t = 0; t < SEQ; ++t) {
        const float* hprev = (t == 0) ? h0 : (out + (size_t)(t - 1) * BD);
        float* outT = out + (size_t)t * BD;

        // xp for my two outputs (written by gemm_xp; same thread rewrites them)
        const float xpL = outT[(size_t)(B0 + bL) * DIM + C0 + c];
        const float xpH = outT[(size_t)(B0 + bH) * DIM + C0 + c];

        float4 acc0 = {0.f, 0.f, 0.f, 0.f};
        float4 acc1 = {0.f, 0.f, 0.f, 0.f};

        // preload chunk 0
        float4 r[8];
        {
            const float* src = hprev + (size_t)(B0 + sb) * DIM + sj0 * 4;
            #pragma unroll
            for (int u = 0; u < 8; ++u) r[u] = *(const float4*)(src + u * 4);
        }

        for (int chunk = 0; chunk < 8; ++chunk) {        // 8 x 128 = 1024 k
            __syncthreads();   // previous chunk's compute done
            #pragma unroll
            for (int u = 0; u < 8; ++u)
                hS4[sb][(sj0 + u) ^ sswz] = r[u];
            __syncthreads();

            // prefetch next chunk while computing this one
            float4 rn[8];
            if (chunk < 7) {
                const float* src = hprev + (size_t)(B0 + sb) * DIM + (chunk + 1) * 128 + sj0 * 4;
                #pragma unroll
                for (int u = 0; u < 8; ++u) rn[u] = *(const float4*)(src + u * 4);
            }

            const int jbase = chunk * 32;
            #pragma unroll
            for (int jj = 0; jj < 32; ++jj) {
                const float4 w4 = *(const float4*)&WhS[jbase + jj][c][0];
                const float4 hL = hS4[bL][jj ^ p];
                const float4 hH = hS4[bH][jj ^ p];
                acc0.x += hL.x * w4.x; acc0.y += hL.y * w4.y;
                acc0.z += hL.z * w4.z; acc0.w += hL.w * w4.w;
                acc1.x += hH.x * w4.x; acc1.y += hH.y * w4.y;
                acc1.z += hH.z * w4.z; acc1.w += hH.w * w4.w;
            }

            if (chunk < 7) {
                #pragma unroll
                for (int u = 0; u < 8; ++u) r[u] = rn[u];
            }
        }

        const float sL = (acc0.x + acc0.y) + (acc0.z + acc0.w) + xpL;
        const float sH = (acc1.x + acc1.y) + (acc1.z + acc1.w) + xpH;
        outT[(size_t)(B0 + bL) * DIM + C0 + c] = tanhf(sL);
        outT[(size_t)(B0 + bH) * DIM + C0 + c] = tanhf(sH);

        if (t < SEQ - 1)
            grid_barrier(bar, (unsigned)(t + 1) * NBLK);
    }
}

// ---------------------------------------------------------------------------
extern "C" void kernel_launch(void* const* d_in, const int* in_sizes, int n_in,
                              void* d_out, int out_size, void* d_ws, size_t ws_size,
                              hipStream_t stream) {
    const float* x  = (const float*)d_in[0];   // [S,B,D]
    const float* h0 = (const float*)d_in[1];   // [B,D]
    const float* Wx = (const float*)d_in[2];   // [D,D]
    const float* Wh = (const float*)d_in[3];   // [D,D]
    const float* b  = (const float*)d_in[4];   // [D]
    float* out = (float*)d_out;                // [S,B,D]
    unsigned* bar = (unsigned*)d_ws;

    // zero the barrier counter (d_ws is poisoned 0xAA before every launch)
    hipMemsetAsync(d_ws, 0, 64, stream);

    // Phase 1: out = x @ Wx + b
    gemm_xp<<<dim3(DIM / 64, (SEQ * BATCH) / 64), 256, 0, stream>>>(x, Wx, b, out);

    // Phase 2: persistent scan with manual grid barrier
    rnn_scan<<<dim3(NBLK), dim3(256), 0, stream>>>(h0, Wh, out, bar);
}

// Round 4
// 2346.723 us; speedup vs baseline: 5.5960x; 5.5960x over previous
//
#include <hip/hip_runtime.h>
#include <math.h>

// RNNLayer: out[t] = tanh(x[t] @ Wx + b + h_{t-1} @ Wh), h_{-1} = h0
// S=128, B=128, D=1024. Inputs/outputs fp32.
//
// Phase 1: gemm_xp (fp32) writes xp = x@Wx + b into d_out.
// Phase 2: ONE persistent kernel, 256 WGs (1/CU), runs all 128 steps.
//   - h @ Wh via MFMA 16x16x32 bf16: h quantized to bf16 per step (staged in
//     LDS), Wh held in REGISTERS as bf16 hi+lo pair (fp32-accurate Wh).
//   - xp read/written in fp32 (exact anchor each step), tanh in fp32.
//   - Grid barrier: flag-array (no contended RMW) + leader-wave-only
//     __threadfence (one L2 wb/inv per CU per step instead of 8+).

#define DIM 1024
#define BATCH 128
#define SEQ 128
#define BD (BATCH * DIM)
#define NBLK 256
#define HSTR 1032   // hS row stride in ushorts (1024 + 8 pad -> (m+q)%8 banks)

typedef __attribute__((ext_vector_type(8))) short bf16x8;
typedef __attribute__((ext_vector_type(4))) float f32x4;

static __device__ __forceinline__ unsigned short f2bf_rne(float f) {
    unsigned u = __builtin_bit_cast(unsigned, f);
    unsigned r = (u + 0x7FFFu + ((u >> 16) & 1u)) >> 16;
    return (unsigned short)r;
}
static __device__ __forceinline__ float bf2f(unsigned short h) {
    return __builtin_bit_cast(float, ((unsigned)h) << 16);
}

// ---------------------------------------------------------------------------
// Phase 1: fp32 GEMM, 64x64 tile (unchanged: ~471 us, 72 TF)
// ---------------------------------------------------------------------------
__global__ __launch_bounds__(256) void gemm_xp(
    const float* __restrict__ A, const float* __restrict__ W,
    const float* __restrict__ bias, float* __restrict__ C)
{
    __shared__ float As[32][68];
    __shared__ float Ws[32][68];

    const int tid  = threadIdx.x;
    const int trow = tid / 16;
    const int tcol = tid % 16;
    const int rowBase = blockIdx.y * 64;
    const int colBase = blockIdx.x * 64;

    const int lam = tid / 8;
    const int laf = tid % 8;
    const int lwk = tid / 16;
    const int lwf = tid % 16;

    float acc[4][4];
    #pragma unroll
    for (int i = 0; i < 4; ++i)
        #pragma unroll
        for (int j = 0; j < 4; ++j) acc[i][j] = 0.f;

    for (int k0 = 0; k0 < DIM; k0 += 32) {
        #pragma unroll
        for (int rr = 0; rr < 2; ++rr) {
            const int m = lam + rr * 32;
            const float4 v = *(const float4*)&A[(size_t)(rowBase + m) * DIM + k0 + laf * 4];
            As[laf * 4 + 0][m] = v.x;
            As[laf * 4 + 1][m] = v.y;
            As[laf * 4 + 2][m] = v.z;
            As[laf * 4 + 3][m] = v.w;
        }
        #pragma unroll
        for (int rr = 0; rr < 2; ++rr) {
            const int k = lwk + rr * 16;
            *(float4*)&Ws[k][lwf * 4] =
                *(const float4*)&W[(size_t)(k0 + k) * DIM + colBase + lwf * 4];
        }
        __syncthreads();

        #pragma unroll
        for (int kk = 0; kk < 32; ++kk) {
            const float4 a4 = *(const float4*)&As[kk][trow * 4];
            const float4 w4 = *(const float4*)&Ws[kk][tcol * 4];
            const float av[4] = {a4.x, a4.y, a4.z, a4.w};
            const float wv[4] = {w4.x, w4.y, w4.z, w4.w};
            #pragma unroll
            for (int i = 0; i < 4; ++i)
                #pragma unroll
                for (int j = 0; j < 4; ++j)
                    acc[i][j] += av[i] * wv[j];
        }
        __syncthreads();
    }

    #pragma unroll
    for (int i = 0; i < 4; ++i) {
        const int row = rowBase + trow * 4 + i;
        const int col = colBase + tcol * 4;
        const float4 bv = *(const float4*)&bias[col];
        float4 o;
        o.x = acc[i][0] + bv.x;
        o.y = acc[i][1] + bv.y;
        o.z = acc[i][2] + bv.z;
        o.w = acc[i][3] + bv.w;
        *(float4*)&C[(size_t)row * DIM + col] = o;
    }
}

// ---------------------------------------------------------------------------
// Phase 2: persistent MFMA scan.
// Block bid: bt = bid>>5 (batch tile of 16 rows), ct2 = bid&31 (32-col slab).
// Wave w: c-tile = (w>>1)*16 within slab; k-half K0 = (w&1)*512.
// Wh bf16 hi/lo resident in regs (16 frags x 2 x 4 VGPR = 128 VGPR).
// Per step: stage h bf16 (16x1024) to LDS; 16 A-reads + 32 MFMAs per wave;
// k-half reduce via LDS; epilogue adds fp32 xp, tanh, writes out[t].
// ---------------------------------------------------------------------------
__global__ __launch_bounds__(256) void rnn_scan(
    const float* __restrict__ h0,
    const float* __restrict__ Wh,
    float* out,
    unsigned* flags)
{
    __shared__ unsigned short hS[16 * HSTR];   // 33 KB: bf16 h tile, padded rows
    __shared__ f32x4 redS[128];                // 2 KB: k-half partial exchange

    const int tid = threadIdx.x;
    const int bid = blockIdx.x;
    const int bt  = bid >> 5;          // 0..7
    const int ct2 = bid & 31;          // 0..31
    const int B0  = bt * 16;
    const int Cb  = ct2 * 32;

    const int w = tid >> 6;            // wave 0..3
    const int l = tid & 63;
    const int n = l & 15;              // output col within 16
    const int q = l >> 4;              // 0..3 (row quad / k-subgroup)
    const int cb = Cb + (w >> 1) * 16; // this wave's 16-col tile base
    const int K0 = (w & 1) * 512;      // this wave's k-half

    // ---- load resident Wh B-fragments (bf16 hi + lo), once ----
    bf16x8 Bhi[16], Blo[16];
    #pragma unroll
    for (int s = 0; s < 16; ++s) {
        bf16x8 hi, lo;
        #pragma unroll
        for (int j = 0; j < 8; ++j) {
            const int k = K0 + 32 * s + q * 8 + j;
            const float wv = Wh[(size_t)k * DIM + cb + n];
            const unsigned short h16 = f2bf_rne(wv);
            hi[j] = (short)h16;
            lo[j] = (short)f2bf_rne(wv - bf2f(h16));
        }
        Bhi[s] = hi;
        Blo[s] = lo;
    }

    // staging mapping: thread (r = tid>>4, u = tid&15); 8 iters of
    // (2 float4 global reads -> 8 bf16 -> one 16B LDS write)
    const int sr = tid >> 4;
    const int su = tid & 15;

    for (int t = 0; t < SEQ; ++t) {
        const float* hsrc = (t == 0) ? (h0 + (size_t)B0 * DIM)
                                     : (out + (size_t)(t - 1) * BD + (size_t)B0 * DIM);
        float* outT = out + (size_t)t * BD;

        // ---- stage h tile (fp32 -> bf16) ----
        {
            const float* srow = hsrc + (size_t)sr * DIM;
            unsigned short* drow = &hS[sr * HSTR];
            #pragma unroll
            for (int i = 0; i < 8; ++i) {
                const int f4 = 2 * su + 32 * i;
                const float4 v0 = *(const float4*)(srow + f4 * 4);
                const float4 v1 = *(const float4*)(srow + f4 * 4 + 4);
                bf16x8 pk;
                pk[0] = (short)f2bf_rne(v0.x); pk[1] = (short)f2bf_rne(v0.y);
                pk[2] = (short)f2bf_rne(v0.z); pk[3] = (short)f2bf_rne(v0.w);
                pk[4] = (short)f2bf_rne(v1.x); pk[5] = (short)f2bf_rne(v1.y);
                pk[6] = (short)f2bf_rne(v1.z); pk[7] = (short)f2bf_rne(v1.w);
                *(bf16x8*)(drow + f4 * 4) = pk;
            }
        }
        __syncthreads();

        // ---- MFMA over this wave's k-half ----
        f32x4 acc = {0.f, 0.f, 0.f, 0.f};
        {
            const unsigned short* hrow = &hS[(l & 15) * HSTR + K0];
            #pragma unroll
            for (int s = 0; s < 16; ++s) {
                const bf16x8 a = *(const bf16x8*)(hrow + 32 * s + 8 * q);
                acc = __builtin_amdgcn_mfma_f32_16x16x32_bf16(a, Bhi[s], acc, 0, 0, 0);
                acc = __builtin_amdgcn_mfma_f32_16x16x32_bf16(a, Blo[s], acc, 0, 0, 0);
            }
        }

        // ---- reduce k-halves: odd waves hand partials to even waves ----
        if (w & 1) redS[(w >> 1) * 64 + l] = acc;
        __syncthreads();

        if (!(w & 1)) {
            const f32x4 p = redS[(w >> 1) * 64 + l];
            // C/D layout: col = lane&15, row = q*4 + reg (m89-verified)
            #pragma unroll
            for (int i = 0; i < 4; ++i) {
                const int row = B0 + q * 4 + i;
                float* po = &outT[(size_t)row * DIM + cb + n];
                const float v = acc[i] + p[i] + *po;   // + fp32 xp
                *po = tanhf(v);
            }
        }

        // ---- grid barrier (skip after last step) ----
        if (t < SEQ - 1) {
            __syncthreads();                 // all stores drained (vmcnt0 @ barrier)
            if (tid < 64) __threadfence();   // leader wave: wb L2 -> visible
            __syncthreads();
            if (tid == 0)
                __hip_atomic_store(&flags[bid * 8], (unsigned)(t + 1),
                                   __ATOMIC_RELAXED, __HIP_MEMORY_SCOPE_AGENT);
            const unsigned* slot = &flags[tid * 8];   // thread i watches block i
            while (__hip_atomic_load(slot, __ATOMIC_RELAXED,
                                     __HIP_MEMORY_SCOPE_AGENT) < (unsigned)(t + 1))
                __builtin_amdgcn_s_sleep(2);
            __syncthreads();
            if (tid < 64) __threadfence();   // leader wave: inv stale L1/L2
            __syncthreads();
        }
    }
}

// ---------------------------------------------------------------------------
extern "C" void kernel_launch(void* const* d_in, const int* in_sizes, int n_in,
                              void* d_out, int out_size, void* d_ws, size_t ws_size,
                              hipStream_t stream) {
    const float* x  = (const float*)d_in[0];   // [S,B,D]
    const float* h0 = (const float*)d_in[1];   // [B,D]
    const float* Wx = (const float*)d_in[2];   // [D,D]
    const float* Wh = (const float*)d_in[3];   // [D,D]
    const float* b  = (const float*)d_in[4];   // [D]
    float* out = (float*)d_out;                // [S,B,D]
    unsigned* flags = (unsigned*)d_ws;         // 256 slots x 32 B

    hipMemsetAsync(d_ws, 0, NBLK * 8 * sizeof(unsigned), stream);

    gemm_xp<<<dim3(DIM / 64, (SEQ * BATCH) / 64), 256, 0, stream>>>(x, Wx, b, out);

    rnn_scan<<<dim3(NBLK), dim3(256), 0, stream>>>(h0, Wh, out, flags);
}

// Round 5
// 2172.559 us; speedup vs baseline: 6.0446x; 1.0802x over previous
//
#include <hip/hip_runtime.h>
#include <math.h>

// RNNLayer: out[t] = tanh(x[t] @ Wx + b + h_{t-1} @ Wh), h_{-1} = h0
// S=128, B=128, D=1024. Inputs/outputs fp32.
//
// Phase 1: gemm_xp (fp32) writes xp = x@Wx + b into d_out.
// Phase 2: ONE persistent kernel, 256 WGs, runs all 128 steps.
//   - h @ Wh via MFMA 16x16x32 bf16; Wh register-resident as bf16 hi+lo.
//   - Cross-block h exchange through out[] using RELAXED AGENT-SCOPE ATOMICS
//     (per-line coherent, L2-bypassing). NO __threadfence anywhere: agent
//     fences on gfx950 emit buffer_wbl2/buffer_inv (full-L2 tag walks,
//     ~5-7us each) which was 95% of round-4's step time.
//   - Ordering: producer drains stores with s_waitcnt vmcnt(0) (asm, memory
//     clobber) before posting its flag; consumer spins on the flag array,
//     then issues bypass loads (in-order issue after the spin branch).

#define DIM 1024
#define BATCH 128
#define SEQ 128
#define BD (BATCH * DIM)
#define NBLK 256
#define HSTR 1032     // hS row stride in ushorts (16B-aligned rows, bank spread)
#define FLAGSTR 16    // uints per flag slot (64 B) to avoid line contention

typedef __attribute__((ext_vector_type(8))) short bf16x8;
typedef __attribute__((ext_vector_type(4))) float f32x4;

static __device__ __forceinline__ unsigned short f2bf_rne(float f) {
    unsigned u = __builtin_bit_cast(unsigned, f);
    unsigned r = (u + 0x7FFFu + ((u >> 16) & 1u)) >> 16;
    return (unsigned short)r;
}
static __device__ __forceinline__ float bf2f(unsigned short h) {
    return __builtin_bit_cast(float, ((unsigned)h) << 16);
}

// ---------------------------------------------------------------------------
// Phase 1: fp32 GEMM, 64x64 tile (unchanged: ~471 us, 72 TF)
// ---------------------------------------------------------------------------
__global__ __launch_bounds__(256) void gemm_xp(
    const float* __restrict__ A, const float* __restrict__ W,
    const float* __restrict__ bias, float* __restrict__ C)
{
    __shared__ float As[32][68];
    __shared__ float Ws[32][68];

    const int tid  = threadIdx.x;
    const int trow = tid / 16;
    const int tcol = tid % 16;
    const int rowBase = blockIdx.y * 64;
    const int colBase = blockIdx.x * 64;

    const int lam = tid / 8;
    const int laf = tid % 8;
    const int lwk = tid / 16;
    const int lwf = tid % 16;

    float acc[4][4];
    #pragma unroll
    for (int i = 0; i < 4; ++i)
        #pragma unroll
        for (int j = 0; j < 4; ++j) acc[i][j] = 0.f;

    for (int k0 = 0; k0 < DIM; k0 += 32) {
        #pragma unroll
        for (int rr = 0; rr < 2; ++rr) {
            const int m = lam + rr * 32;
            const float4 v = *(const float4*)&A[(size_t)(rowBase + m) * DIM + k0 + laf * 4];
            As[laf * 4 + 0][m] = v.x;
            As[laf * 4 + 1][m] = v.y;
            As[laf * 4 + 2][m] = v.z;
            As[laf * 4 + 3][m] = v.w;
        }
        #pragma unroll
        for (int rr = 0; rr < 2; ++rr) {
            const int k = lwk + rr * 16;
            *(float4*)&Ws[k][lwf * 4] =
                *(const float4*)&W[(size_t)(k0 + k) * DIM + colBase + lwf * 4];
        }
        __syncthreads();

        #pragma unroll
        for (int kk = 0; kk < 32; ++kk) {
            const float4 a4 = *(const float4*)&As[kk][trow * 4];
            const float4 w4 = *(const float4*)&Ws[kk][tcol * 4];
            const float av[4] = {a4.x, a4.y, a4.z, a4.w};
            const float wv[4] = {w4.x, w4.y, w4.z, w4.w};
            #pragma unroll
            for (int i = 0; i < 4; ++i)
                #pragma unroll
                for (int j = 0; j < 4; ++j)
                    acc[i][j] += av[i] * wv[j];
        }
        __syncthreads();
    }

    #pragma unroll
    for (int i = 0; i < 4; ++i) {
        const int row = rowBase + trow * 4 + i;
        const int col = colBase + tcol * 4;
        const float4 bv = *(const float4*)&bias[col];
        float4 o;
        o.x = acc[i][0] + bv.x;
        o.y = acc[i][1] + bv.y;
        o.z = acc[i][2] + bv.z;
        o.w = acc[i][3] + bv.w;
        *(float4*)&C[(size_t)row * DIM + col] = o;
    }
}

// ---------------------------------------------------------------------------
// Phase 2: persistent MFMA scan, fence-free coherence.
// Block bid: bt = bid>>5 (16 batch rows), ct2 = bid&31 (32-col slab).
// Wave w: 16-col tile (w>>1), k-half (w&1). Wh bf16 hi/lo in registers.
// ---------------------------------------------------------------------------
__global__ __launch_bounds__(256) void rnn_scan(
    const float* __restrict__ h0,
    const float* __restrict__ Wh,
    float* out,
    unsigned* flags)
{
    __shared__ unsigned short hS[16 * HSTR];   // 33 KB bf16 h tile
    __shared__ f32x4 redS[128];                // 2 KB k-half exchange

    const int tid = threadIdx.x;
    const int bid = blockIdx.x;
    const int bt  = bid >> 5;
    const int ct2 = bid & 31;
    const int B0  = bt * 16;
    const int Cb  = ct2 * 32;

    const int w = tid >> 6;
    const int l = tid & 63;
    const int n = l & 15;
    const int q = l >> 4;
    const int cb = Cb + (w >> 1) * 16;
    const int K0 = (w & 1) * 512;

    // ---- resident Wh B-fragments (bf16 hi + lo), loaded once ----
    bf16x8 Bhi[16], Blo[16];
    #pragma unroll
    for (int s = 0; s < 16; ++s) {
        bf16x8 hi, lo;
        #pragma unroll
        for (int j = 0; j < 8; ++j) {
            const int k = K0 + 32 * s + q * 8 + j;
            const float wv = Wh[(size_t)k * DIM + cb + n];
            const unsigned short h16 = f2bf_rne(wv);
            hi[j] = (short)h16;
            lo[j] = (short)f2bf_rne(wv - bf2f(h16));
        }
        Bhi[s] = hi;
        Blo[s] = lo;
    }

    const int sr = tid >> 4;    // staging: row 0..15
    const int su = tid & 15;    // staging: ulong lane within row

    for (int t = 0; t < SEQ; ++t) {
        const float* hsrc = (t == 0) ? (h0 + (size_t)B0 * DIM)
                                     : (out + (size_t)(t - 1) * BD + (size_t)B0 * DIM);
        float* outT = out + (size_t)t * BD;

        // ---- stage h tile: coherent 8B bypass loads -> bf16 -> LDS ----
        {
            const unsigned long long* srow =
                (const unsigned long long*)(hsrc + (size_t)sr * DIM);
            unsigned short* drow = &hS[sr * HSTR];
            #pragma unroll
            for (int i = 0; i < 32; ++i) {
                const unsigned long long v = __hip_atomic_load(
                    srow + su + 16 * i, __ATOMIC_RELAXED, __HIP_MEMORY_SCOPE_AGENT);
                const float f0 = __builtin_bit_cast(float, (unsigned)(v & 0xFFFFFFFFull));
                const float f1 = __builtin_bit_cast(float, (unsigned)(v >> 32));
                const unsigned pk =
                    (unsigned)f2bf_rne(f0) | ((unsigned)f2bf_rne(f1) << 16);
                *(unsigned*)(drow + 2 * (su + 16 * i)) = pk;
            }
        }

        // ---- xp prefetch (even waves; same thread rewrites these) ----
        float xpv[4];
        if (!(w & 1)) {
            #pragma unroll
            for (int i = 0; i < 4; ++i)
                xpv[i] = __builtin_nontemporal_load(
                    &outT[(size_t)(B0 + q * 4 + i) * DIM + cb + n]);
        }

        __syncthreads();

        // ---- MFMA over this wave's k-half ----
        f32x4 acc = {0.f, 0.f, 0.f, 0.f};
        {
            const unsigned short* hrow = &hS[(l & 15) * HSTR + K0];
            #pragma unroll
            for (int s = 0; s < 16; ++s) {
                const bf16x8 a = *(const bf16x8*)(hrow + 32 * s + 8 * q);
                acc = __builtin_amdgcn_mfma_f32_16x16x32_bf16(a, Bhi[s], acc, 0, 0, 0);
                acc = __builtin_amdgcn_mfma_f32_16x16x32_bf16(a, Blo[s], acc, 0, 0, 0);
            }
        }

        // ---- reduce k-halves: odd waves hand partials to even waves ----
        if (w & 1) redS[(w >> 1) * 64 + l] = acc;
        __syncthreads();

        if (!(w & 1)) {
            const f32x4 p = redS[(w >> 1) * 64 + l];
            // C/D layout: col = lane&15, row = q*4 + reg
            #pragma unroll
            for (int i = 0; i < 4; ++i) {
                const float v = tanhf(acc[i] + p[i] + xpv[i]);
                // coherent write-through store: visible at IC, no fence needed
                __hip_atomic_store(&outT[(size_t)(B0 + q * 4 + i) * DIM + cb + n],
                                   v, __ATOMIC_RELAXED, __HIP_MEMORY_SCOPE_AGENT);
            }
        }

        // ---- fence-free grid barrier ----
        if (t < SEQ - 1) {
            // drain my wave's stores to the coherence point before arriving
            asm volatile("s_waitcnt vmcnt(0)" ::: "memory");
            __syncthreads();   // all waves' stores drained
            if (tid == 0)
                __hip_atomic_store(&flags[bid * FLAGSTR], (unsigned)(t + 1),
                                   __ATOMIC_RELAXED, __HIP_MEMORY_SCOPE_AGENT);
            // thread i watches block i; block proceeds when all 256 flags land
            const unsigned* slot = &flags[tid * FLAGSTR];
            while (__hip_atomic_load(slot, __ATOMIC_RELAXED,
                                     __HIP_MEMORY_SCOPE_AGENT) < (unsigned)(t + 1))
                __builtin_amdgcn_s_sleep(2);
            __syncthreads();
        }
    }
}

// ---------------------------------------------------------------------------
extern "C" void kernel_launch(void* const* d_in, const int* in_sizes, int n_in,
                              void* d_out, int out_size, void* d_ws, size_t ws_size,
                              hipStream_t stream) {
    const float* x  = (const float*)d_in[0];   // [S,B,D]
    const float* h0 = (const float*)d_in[1];   // [B,D]
    const float* Wx = (const float*)d_in[2];   // [D,D]
    const float* Wh = (const float*)d_in[3];   // [D,D]
    const float* b  = (const float*)d_in[4];   // [D]
    float* out = (float*)d_out;                // [S,B,D]
    unsigned* flags = (unsigned*)d_ws;         // 256 slots x 64 B

    hipMemsetAsync(d_ws, 0, NBLK * FLAGSTR * sizeof(unsigned), stream);

    gemm_xp<<<dim3(DIM / 64, (SEQ * BATCH) / 64), 256, 0, stream>>>(x, Wx, b, out);

    rnn_scan<<<dim3(NBLK), dim3(256), 0, stream>>>(h0, Wh, out, flags);
}